// Round 12
// baseline (281.488 us; speedup 1.0000x reference)
//
#include <hip/hip_runtime.h>
#include <hip/hip_bf16.h>
#include <stdint.h>

// eidosNeighborMixer on MI355X:
//   pass 0a: W' = rotate(W, theta0+theta1) folded, transposed to Wt[N][K], bf16
//   pass 0b: b' = rotate(b); zero page
//   pass 0c: xbp = bf16(x) with zero rows at s'=0 and s'=8193 (padded seq)
//   pass 1 : GEMM  out = A @ Wt^T + b'   (A[m,k] = xbp[b][s + k/1024][k%1024])
//            256x128 block tile, BK=32, 8 waves (4Mx2N, 512 thr), wave 64x64
//            (acc 64 VGPR). 3-deep LDS ring = 72 KiB -> TWO blocks per CU
//            (1024 thr, 16 waves, 144 KiB: all resources at <=50% of HW
//            limits, unlike R11's exact-2048-thread boundary which failed to
//            co-schedule). Counted vmcnt(3) staging lead of 2 K-tiles;
//            cross-block phase drift overlaps LDS bursts with MFMA bursts.
//   pass 2 : grouped (d%7) RMS norm, in-place on d_out

#define SEQ 8192
#define NB 4
#define DM 1024
#define KD 3072

typedef __attribute__((ext_vector_type(8))) short short8_t;
typedef __attribute__((ext_vector_type(4))) float f32x4;

__device__ __forceinline__ unsigned short f2bf(float f) {
  union { float f; uint32_t u; } v; v.f = f;
  return (unsigned short)((v.u + 0x7fffu + ((v.u >> 16) & 1u)) >> 16);  // RNE
}

__device__ __forceinline__ void async_ld16(const void* g, void* l) {
  __builtin_amdgcn_global_load_lds(
      (const __attribute__((address_space(1))) uint32_t*)g,
      (__attribute__((address_space(3))) uint32_t*)(uint32_t)(uintptr_t)l,
      16, 0, 0);
}

// ---------------- prep: rotate+transpose W -> Wt[N][K] bf16 ----------------
__global__ __launch_bounds__(256) void prep_w(const float* __restrict__ W,
                                              const float* __restrict__ theta,
                                              unsigned short* __restrict__ Wt) {
  __shared__ float csc[32], css[32];
  __shared__ unsigned short tile[64][72];  // [n_local][k_local], padded
  const int bk = blockIdx.x % 48, bn = blockIdx.x / 48;
  const int k0 = bk * 64, n0 = bn * 64;
  const int t = threadIdx.x;
  if (t < 32) {
    int d = n0 / 2 + t;
    float ang = theta[d] + theta[512 + d];
    csc[t] = cosf(ang); css[t] = sinf(ang);
  }
  __syncthreads();
#pragma unroll
  for (int i = 0; i < 8; ++i) {
    int idx = i * 256 + t;           // 2048 pairs = 64 k-rows x 32 pairs
    int pr = idx >> 5;               // k row 0..63
    int pc = idx & 31;               // pair col 0..31
    const float2 w2 = *(const float2*)&W[(size_t)(k0 + pr) * DM + n0 + pc * 2];
    float c = csc[pc], s = css[pc];
    tile[pc * 2][pr]     = f2bf(w2.x * c - w2.y * s);
    tile[pc * 2 + 1][pr] = f2bf(w2.x * s + w2.y * c);
  }
  __syncthreads();
#pragma unroll
  for (int i = 0; i < 16; ++i) {
    int idx = i * 256 + t;           // 4096 elems
    int r = idx >> 6, cdx = idx & 63;
    Wt[(size_t)(n0 + r) * KD + k0 + cdx] = tile[r][cdx];
  }
}

// ---------------- prep: rotated bias + zero page ----------------
__global__ void prep_bias(const float* __restrict__ b, const float* __restrict__ theta,
                          float* __restrict__ biasp, float* __restrict__ zp) {
  const int t = threadIdx.x;  // 512
  float ang = theta[t] + theta[512 + t];
  float c = cosf(ang), s = sinf(ang);
  float be = b[2 * t], bo = b[2 * t + 1];
  biasp[2 * t]     = be * c - bo * s;
  biasp[2 * t + 1] = be * s + bo * c;
  if (t < 256) ((float4*)zp)[t] = make_float4(0.f, 0.f, 0.f, 0.f);
}

// ---------------- prep: x -> bf16, seq-padded ----------------
__global__ __launch_bounds__(256) void prep_x(const float* __restrict__ x,
                                              unsigned short* __restrict__ xbp) {
  const size_t total = (size_t)NB * 8194 * 128;  // 16B chunks (8 bf16)
  for (size_t i = (size_t)blockIdx.x * 256 + threadIdx.x; i < total;
       i += (size_t)gridDim.x * 256) {
    int d8 = (int)(i & 127);
    size_t rem = i >> 7;
    int sp = (int)(rem % 8194);
    size_t bb = rem / 8194;
    uint4 o = make_uint4(0u, 0u, 0u, 0u);
    if (sp > 0 && sp < 8193) {
      const float4* src = (const float4*)(x + (bb * SEQ + (size_t)(sp - 1)) * DM + d8 * 8);
      float4 lo = src[0], hi = src[1];
      o.x = (uint32_t)f2bf(lo.x) | ((uint32_t)f2bf(lo.y) << 16);
      o.y = (uint32_t)f2bf(lo.z) | ((uint32_t)f2bf(lo.w) << 16);
      o.z = (uint32_t)f2bf(hi.x) | ((uint32_t)f2bf(hi.y) << 16);
      o.w = (uint32_t)f2bf(hi.z) | ((uint32_t)f2bf(hi.w) << 16);
    }
    ((uint4*)xbp)[i] = o;
  }
}

// ---- GEMM: 256x128 block, BK=32, 8 waves x (64x64), 3-ring, 2 blocks/CU ---
__global__ __launch_bounds__(512, 4) void gemm256(const unsigned short* __restrict__ xbp,
                                                  const unsigned short* __restrict__ Wt,
                                                  const float* __restrict__ biasp,
                                                  float* __restrict__ out) {
  __shared__ __align__(16) unsigned char As[3][16384];  // [buf][256 rows][32 bf16]
  __shared__ __align__(16) unsigned char Bs[3][8192];   // [buf][128 nrow][32 bf16]

  const int tid = threadIdx.x;
  const int lane = tid & 63;
  const int wid = tid >> 6;                   // 0..7
  const int wm = wid >> 1, wn = wid & 1;      // 4M x 2N wave grid
  const int row16 = lane & 15, kgrp = lane >> 4;

  // XCD-bijective swizzle: 1024 blocks = 8 XCD x (16 mtiles x 8 ntiles),
  // ntile fastest -> consecutive same-XCD blocks share the A panel (L2).
  const int L = blockIdx.x;
  const int xcd = L & 7;
  const int j = L >> 3;                        // 0..127
  const int mtile = xcd * 16 + (j >> 3);       // 0..127
  const int ntile = j & 7;                     // 0..7

  const int n0 = ntile * 128;
  const int batch = mtile >> 5;
  const int s0 = (mtile & 31) * 256;
  const size_t m0 = (size_t)mtile * 256;

  // fragment LDS byte offsets (thread-constant), XOR chunk swizzle
  int aoff[4], boff[4];
#pragma unroll
  for (int mi = 0; mi < 4; ++mi) {
    int r = wm * 64 + mi * 16 + row16;
    aoff[mi] = r * 64 + (kgrp ^ ((r >> 1) & 3)) * 16;
  }
#pragma unroll
  for (int ni = 0; ni < 4; ++ni) {
    int r = wn * 64 + ni * 16 + row16;
    boff[ni] = r * 64 + (kgrp ^ ((r >> 1) & 3)) * 16;
  }

  // staging: LDS dest LINEAR; global source chunk pre-swizzled (same XOR).
  // A: 1024 x 16B (2/thread). B: 512 x 16B (1/thread).
  auto stageA = [&](int kt, int buf) {
    const int c = kt >> 5;
    const int ksb = (kt & 31) * 32;
    const size_t base = ((size_t)batch * 8194 + (size_t)(s0 + c)) * DM + ksb;
#pragma unroll
    for (int i = 0; i < 2; ++i) {
      int idx = i * 512 + tid;
      int row = idx >> 2, c16 = idx & 3;
      int cs = c16 ^ ((row >> 1) & 3);
      async_ld16(xbp + base + (size_t)row * DM + cs * 8, &As[buf][idx * 16]);
    }
  };
  auto stageB = [&](int kt, int buf) {
    const int kb = kt * 32;
    int row = tid >> 2, c16 = tid & 3;
    int cs = c16 ^ ((row >> 1) & 3);
    async_ld16(Wt + (size_t)(n0 + row) * KD + kb + cs * 8, &Bs[buf][tid * 16]);
  };

  f32x4 acc[4][4];
#pragma unroll
  for (int a = 0; a < 4; ++a)
#pragma unroll
    for (int b = 0; b < 4; ++b) acc[a][b] = (f32x4){0.f, 0.f, 0.f, 0.f};

  // prologue: stage kt 0,1,2 (3 loads each per thread); confirm kt0; barrier
  stageA(0, 0); stageB(0, 0);
  stageA(1, 1); stageB(1, 1);
  stageA(2, 2); stageB(2, 2);
  asm volatile("s_waitcnt vmcnt(6)" ::: "memory");
  __builtin_amdgcn_s_barrier();

  // per K-tile: stage kt+2 (buf (kt+2)%3 — WAR-safe, its readers finished at
  // kt-1's barrier), read own 8 frags, lgkm(0) (cross-block TLP hides it),
  // 16 MFMA under setprio, counted vmcnt(3) (keeps stage kt+2 in flight),
  // barrier.
  auto body = [&](int kt, int buf, int doStage, int vmN) {
    if (doStage) {
      const int sbuf = (buf + 2) % 3;
      stageA(kt + 2, sbuf); stageB(kt + 2, sbuf);
    }
    short8_t af[4], bf[4];
#pragma unroll
    for (int mi = 0; mi < 4; ++mi)
      af[mi] = *(const short8_t*)(&As[buf][0] + aoff[mi]);
#pragma unroll
    for (int ni = 0; ni < 4; ++ni)
      bf[ni] = *(const short8_t*)(&Bs[buf][0] + boff[ni]);
    asm volatile("s_waitcnt lgkmcnt(0)" ::: "memory");
    __builtin_amdgcn_sched_barrier(0);
    __builtin_amdgcn_s_setprio(1);
#pragma unroll
    for (int mi = 0; mi < 4; ++mi)
#pragma unroll
      for (int ni = 0; ni < 4; ++ni)
        acc[mi][ni] = __builtin_amdgcn_mfma_f32_16x16x32_bf16(
            af[mi], bf[ni], acc[mi][ni], 0, 0, 0);
    __builtin_amdgcn_s_setprio(0);
    if (vmN == 3)      asm volatile("s_waitcnt vmcnt(3)" ::: "memory");
    else               asm volatile("s_waitcnt vmcnt(0)" ::: "memory");
    __builtin_amdgcn_sched_barrier(0);
    __builtin_amdgcn_s_barrier();
  };

  for (int kt3 = 0; kt3 < 93; kt3 += 3) {      // kt 0..92
    body(kt3 + 0, 0, 1, 3);
    body(kt3 + 1, 1, 1, 3);
    body(kt3 + 2, 2, 1, 3);
  }
  body(93, 0, 1, 3);                           // stages kt95 -> buf 2
  body(94, 1, 0, 0);
  body(95, 2, 0, 0);

  // epilogue: C[row=kgrp*4+r, col=row16] per 16x16 fragment
#pragma unroll
  for (int mi = 0; mi < 4; ++mi) {
    size_t grow = m0 + (size_t)(wm * 64 + mi * 16 + kgrp * 4);
#pragma unroll
    for (int ni = 0; ni < 4; ++ni) {
      int col = n0 + wn * 64 + ni * 16 + row16;
      float bia = biasp[col];
      float* op = out + grow * DM + col;
#pragma unroll
      for (int r = 0; r < 4; ++r) op[(size_t)r * DM] = acc[mi][ni][r] + bia;
    }
  }
}

// ---------------- fallback GEMM (fp32 A direct), 128x128 2-barrier ----------
__global__ __launch_bounds__(256) void gemm_fb(const float* __restrict__ Ag,
                                               const unsigned short* __restrict__ Wt,
                                               const float* __restrict__ biasp,
                                               const float* __restrict__ zp,
                                               float* __restrict__ out) {
  __shared__ __align__(16) unsigned char As[128 * 64 * 4];
  __shared__ __align__(16) unsigned char Bs[128 * 64 * 2];

  const int tid = threadIdx.x;
  const int lane = tid & 63;
  const int wid = tid >> 6;
  const int wm = wid >> 1, wn = wid & 1;
  const int row16 = lane & 15, kgrp = lane >> 4;

  const int L = blockIdx.x;
  const int xcd = L & 7;
  const int j = L >> 3;
  const int mtile = xcd * 32 + (j >> 3);
  const int ntile = j & 7;

  const int n0 = ntile * 128;
  const int batch = mtile >> 6;
  const int s0 = (mtile & 63) * 128;
  const size_t m0 = (size_t)mtile * 128;

  f32x4 acc[4][4];
#pragma unroll
  for (int a = 0; a < 4; ++a)
#pragma unroll
    for (int b = 0; b < 4; ++b) acc[a][b] = (f32x4){0.f, 0.f, 0.f, 0.f};

  for (int kt = 0; kt < 48; ++kt) {
    const int c = kt >> 4;
    const int ksb = (kt & 15) * 64;
    __syncthreads();
#pragma unroll
    for (int it = 0; it < 8; ++it) {
      int f16 = it * 256 + tid;
      int row = f16 >> 4, c16 = f16 & 15;
      int c16s = c16 ^ (row & 7);
      int s = s0 + row + c - 1;
      const float* src = (s >= 0 && s < SEQ)
          ? Ag + ((size_t)batch * SEQ + (size_t)s) * DM + ksb + c16s * 4
          : zp + c16s * 4;
      async_ld16(src, As + f16 * 16);
    }
#pragma unroll
    for (int it = 0; it < 4; ++it) {
      int f16 = it * 256 + tid;
      int row = f16 >> 3, c16 = f16 & 7;
      int c16s = c16 ^ (row & 7);
      const unsigned short* src = Wt + (size_t)(n0 + row) * KD + kt * 64 + c16s * 8;
      async_ld16(src, Bs + f16 * 16);
    }
    __syncthreads();

#pragma unroll
    for (int kk = 0; kk < 2; ++kk) {
      short8_t af[4], bfr[4];
#pragma unroll
      for (int mi = 0; mi < 4; ++mi) {
        int r = wm * 64 + mi * 16 + row16;
        int kb = kk * 128 + kgrp * 32;
        f32x4 lo = *(const f32x4*)(As + r * 256 + (kb ^ ((r & 7) << 4)));
        f32x4 hi = *(const f32x4*)(As + r * 256 + ((kb + 16) ^ ((r & 7) << 4)));
        union { short8_t v; unsigned short u[8]; } pk;
        pk.u[0] = f2bf(lo[0]); pk.u[1] = f2bf(lo[1]);
        pk.u[2] = f2bf(lo[2]); pk.u[3] = f2bf(lo[3]);
        pk.u[4] = f2bf(hi[0]); pk.u[5] = f2bf(hi[1]);
        pk.u[6] = f2bf(hi[2]); pk.u[7] = f2bf(hi[3]);
        af[mi] = pk.v;
      }
#pragma unroll
      for (int ni = 0; ni < 4; ++ni) {
        int r = wn * 64 + ni * 16 + row16;
        int kb = kk * 64 + kgrp * 16;
        bfr[ni] = *(const short8_t*)(Bs + r * 128 + (kb ^ ((r & 7) << 4)));
      }
#pragma unroll
      for (int mi = 0; mi < 4; ++mi)
#pragma unroll
        for (int ni = 0; ni < 4; ++ni)
          acc[mi][ni] = __builtin_amdgcn_mfma_f32_16x16x32_bf16(
              af[mi], bfr[ni], acc[mi][ni], 0, 0, 0);
    }
  }

#pragma unroll
  for (int mi = 0; mi < 4; ++mi) {
    size_t grow = m0 + (size_t)(wm * 64 + mi * 16 + kgrp * 4);
#pragma unroll
    for (int ni = 0; ni < 4; ++ni) {
      int col = n0 + wn * 64 + ni * 16 + row16;
      float bia = biasp[col];
      float* op = out + grow * DM + col;
#pragma unroll
      for (int r = 0; r < 4; ++r) op[(size_t)r * DM] = acc[mi][ni][r] + bia;
    }
  }
}

// ---------------- pass 2: grouped (d%7) RMS norm, in-place ----------------
__global__ __launch_bounds__(256) void norm_kernel(float* __restrict__ y,
                                                   const float* __restrict__ gamma) {
  const int tid = threadIdx.x, lane = tid & 63, wv = tid >> 6;
  const size_t row = (size_t)blockIdx.x * 4 + wv;   // one wave per row
  float4* rp = (float4*)(y + row * DM);
  const float4* gp = (const float4*)gamma;
  float4 v[4];
#pragma unroll
  for (int jj = 0; jj < 4; ++jj) v[jj] = rp[jj * 64 + lane];

  float ss[7] = {0.f, 0.f, 0.f, 0.f, 0.f, 0.f, 0.f};
#pragma unroll
  for (int jj = 0; jj < 4; ++jj) {
    const float vv[4] = {v[jj].x, v[jj].y, v[jj].z, v[jj].w};
#pragma unroll
    for (int i = 0; i < 4; ++i) {
      int d = (jj * 64 + lane) * 4 + i;
      int g = d % 7;
      float sq = vv[i] * vv[i];
#pragma unroll
      for (int t = 0; t < 7; ++t) ss[t] += (g == t) ? sq : 0.f;
    }
  }
#pragma unroll
  for (int t = 0; t < 7; ++t) {
#pragma unroll
    for (int off = 32; off >= 1; off >>= 1) ss[t] += __shfl_xor(ss[t], off, 64);
  }
  float inv[7];
#pragma unroll
  for (int t = 0; t < 7; ++t) {
    float cnt = (t < 2) ? 147.f : 146.f;   // D=1024: groups 0,1 have 147 dims
    inv[t] = rsqrtf(ss[t] / cnt + 1e-6f);
  }
#pragma unroll
  for (int jj = 0; jj < 4; ++jj) {
    float4 g4 = gp[jj * 64 + lane];
    const float vv[4] = {v[jj].x, v[jj].y, v[jj].z, v[jj].w};
    const float gg[4] = {g4.x, g4.y, g4.z, g4.w};
    float o[4];
#pragma unroll
    for (int i = 0; i < 4; ++i) {
      int d = (jj * 64 + lane) * 4 + i;
      int g = d % 7;
      float iv = inv[0];
#pragma unroll
      for (int t = 1; t < 7; ++t) iv = (g == t) ? inv[t] : iv;
      o[i] = vv[i] * iv * gg[i];
    }
    rp[jj * 64 + lane] = make_float4(o[0], o[1], o[2], o[3]);
  }
}

extern "C" void kernel_launch(void* const* d_in, const int* in_sizes, int n_in,
                              void* d_out, int out_size, void* d_ws, size_t ws_size,
                              hipStream_t stream) {
  const float* x     = (const float*)d_in[0];
  const float* W     = (const float*)d_in[1];
  const float* b     = (const float*)d_in[2];
  const float* theta = (const float*)d_in[3];
  const float* gamma = (const float*)d_in[4];
  float* out = (float*)d_out;
  (void)in_sizes; (void)n_in; (void)out_size;

  char* ws = (char*)d_ws;
  unsigned short* Wt = (unsigned short*)ws;                 // 6,291,456 B
  float* biasp = (float*)(ws + 6291456);                    // 4 KiB
  float* zp    = (float*)(ws + 6291456 + 4096);             // 4 KiB zeros
  unsigned short* xbp = (unsigned short*)(ws + 6299648);    // 67,158,016 B
  const size_t needA = 6299648 + (size_t)NB * 8194 * DM * 2;

  prep_w<<<dim3(768), dim3(256), 0, stream>>>(W, theta, Wt);
  prep_bias<<<dim3(1), dim3(512), 0, stream>>>(b, theta, biasp, zp);

  if (ws_size >= needA) {
    prep_x<<<dim3(4096), dim3(256), 0, stream>>>(x, xbp);
    gemm256<<<dim3(1024), dim3(512), 0, stream>>>(xbp, Wt, biasp, out);
  } else {
    gemm_fb<<<dim3(2048), dim3(256), 0, stream>>>(x, Wt, biasp, zp, out);
  }
  norm_kernel<<<dim3(8192), dim3(256), 0, stream>>>(out, gamma);
}

// Round 13
// 259.560 us; speedup vs baseline: 1.0845x; 1.0845x over previous
//
#include <hip/hip_runtime.h>
#include <hip/hip_bf16.h>
#include <stdint.h>

// eidosNeighborMixer on MI355X:
//   pass 0a: W' = rotate(W, theta0+theta1) folded, transposed to Wt[N][K], bf16
//   pass 0b: b' = rotate(b); zero page
//   pass 0c: xbp = bf16(x) with zero rows at s'=0 and s'=8193 (padded seq)
//   pass 1 : GEMM  out = A @ Wt^T + b'   (A[m,k] = xbp[b][s + k/1024][k%1024])
//            8-PHASE template (m201 port): 256x256 tile, BK=64, 8 waves
//            (2Mx4N, wave 128x64), 2 double-buffers (128 KiB LDS).
//            Per phase: {4 wave-local global_load_lds staging | 4-8 ds_read |
//            barrier | lgkm(0) | setprio(1) 16 MFMA setprio(0) | barrier}.
//            vmcnt(0) only at phases 3/7 (drains 1-3-phase-old loads, cheap).
//            LDS rows 128B with chunk ^= (row&7) XOR swizzle: every 16-lane
//            quarter covers all 8 granules x2 = conflict-free; staging keeps
//            linear LDS dest + pre-swizzled global source.
//   pass 2 : grouped (d%7) RMS norm, in-place on d_out

#define SEQ 8192
#define NB 4
#define DM 1024
#define KD 3072

typedef __attribute__((ext_vector_type(8))) short short8_t;
typedef __attribute__((ext_vector_type(4))) float f32x4;

__device__ __forceinline__ unsigned short f2bf(float f) {
  union { float f; uint32_t u; } v; v.f = f;
  return (unsigned short)((v.u + 0x7fffu + ((v.u >> 16) & 1u)) >> 16);  // RNE
}

__device__ __forceinline__ void async_ld16(const void* g, void* l) {
  __builtin_amdgcn_global_load_lds(
      (const __attribute__((address_space(1))) uint32_t*)g,
      (__attribute__((address_space(3))) uint32_t*)(uint32_t)(uintptr_t)l,
      16, 0, 0);
}

// ---------------- prep: rotate+transpose W -> Wt[N][K] bf16 ----------------
__global__ __launch_bounds__(256) void prep_w(const float* __restrict__ W,
                                              const float* __restrict__ theta,
                                              unsigned short* __restrict__ Wt) {
  __shared__ float csc[32], css[32];
  __shared__ unsigned short tile[64][72];  // [n_local][k_local], padded
  const int bk = blockIdx.x % 48, bn = blockIdx.x / 48;
  const int k0 = bk * 64, n0 = bn * 64;
  const int t = threadIdx.x;
  if (t < 32) {
    int d = n0 / 2 + t;
    float ang = theta[d] + theta[512 + d];
    csc[t] = cosf(ang); css[t] = sinf(ang);
  }
  __syncthreads();
#pragma unroll
  for (int i = 0; i < 8; ++i) {
    int idx = i * 256 + t;           // 2048 pairs = 64 k-rows x 32 pairs
    int pr = idx >> 5;               // k row 0..63
    int pc = idx & 31;               // pair col 0..31
    const float2 w2 = *(const float2*)&W[(size_t)(k0 + pr) * DM + n0 + pc * 2];
    float c = csc[pc], s = css[pc];
    tile[pc * 2][pr]     = f2bf(w2.x * c - w2.y * s);
    tile[pc * 2 + 1][pr] = f2bf(w2.x * s + w2.y * c);
  }
  __syncthreads();
#pragma unroll
  for (int i = 0; i < 16; ++i) {
    int idx = i * 256 + t;           // 4096 elems
    int r = idx >> 6, cdx = idx & 63;
    Wt[(size_t)(n0 + r) * KD + k0 + cdx] = tile[r][cdx];
  }
}

// ---------------- prep: rotated bias + zero page ----------------
__global__ void prep_bias(const float* __restrict__ b, const float* __restrict__ theta,
                          float* __restrict__ biasp, float* __restrict__ zp) {
  const int t = threadIdx.x;  // 512
  float ang = theta[t] + theta[512 + t];
  float c = cosf(ang), s = sinf(ang);
  float be = b[2 * t], bo = b[2 * t + 1];
  biasp[2 * t]     = be * c - bo * s;
  biasp[2 * t + 1] = be * s + bo * c;
  if (t < 256) ((float4*)zp)[t] = make_float4(0.f, 0.f, 0.f, 0.f);
}

// ---------------- prep: x -> bf16, seq-padded ----------------
__global__ __launch_bounds__(256) void prep_x(const float* __restrict__ x,
                                              unsigned short* __restrict__ xbp) {
  const size_t total = (size_t)NB * 8194 * 128;  // 16B chunks (8 bf16)
  for (size_t i = (size_t)blockIdx.x * 256 + threadIdx.x; i < total;
       i += (size_t)gridDim.x * 256) {
    int d8 = (int)(i & 127);
    size_t rem = i >> 7;
    int sp = (int)(rem % 8194);
    size_t bb = rem / 8194;
    uint4 o = make_uint4(0u, 0u, 0u, 0u);
    if (sp > 0 && sp < 8193) {
      const float4* src = (const float4*)(x + (bb * SEQ + (size_t)(sp - 1)) * DM + d8 * 8);
      float4 lo = src[0], hi = src[1];
      o.x = (uint32_t)f2bf(lo.x) | ((uint32_t)f2bf(lo.y) << 16);
      o.y = (uint32_t)f2bf(lo.z) | ((uint32_t)f2bf(lo.w) << 16);
      o.z = (uint32_t)f2bf(hi.x) | ((uint32_t)f2bf(hi.y) << 16);
      o.w = (uint32_t)f2bf(hi.z) | ((uint32_t)f2bf(hi.w) << 16);
    }
    ((uint4*)xbp)[i] = o;
  }
}

// ---- GEMM: 8-phase 256x256, BK=64, 8 waves, 2 dbuf, wave-local staging ----
__global__ __launch_bounds__(512, 2) void gemm256(const unsigned short* __restrict__ xbp,
                                                  const unsigned short* __restrict__ Wt,
                                                  const float* __restrict__ biasp,
                                                  float* __restrict__ out) {
  // [db][half][128 rows][64 bf16 = 128 B]
  __shared__ __align__(16) unsigned char As[2][2][16384];
  __shared__ __align__(16) unsigned char Bs[2][2][16384];

  const int tid = threadIdx.x;
  const int lane = tid & 63;
  const int wid = tid >> 6;                   // 0..7
  const int wm = wid >> 2, wn = wid & 3;      // 2M x 4N wave grid
  const int row16 = lane & 15, kgrp = lane >> 4;

  // XCD-bijective swizzle: 512 blocks = 8 XCD x (16 mtiles x 4 ntiles)
  const int L = blockIdx.x;
  const int xcd = L & 7;
  const int j = L >> 3;
  const int mtile = xcd * 16 + (j >> 2);      // 0..127
  const int ntile = j & 3;                    // 0..3

  const int n0 = ntile * 256;
  const int batch = mtile >> 5;
  const int s0 = (mtile & 31) * 256;
  const size_t m0 = (size_t)mtile * 256;

  // ---- wave-local staging: each wave stages its own A-half and B-half ----
  // A-half(wm) of K-step kt: 16 KiB staged by the 4 waves sharing wm,
  // each wave covers chunks idx = wn*256 + i*64 + lane (4 loads).
  auto stageA = [&](int kt, int db) {
    const int c = kt >> 4, ksb = (kt & 15) * 64;
    const size_t base =
        ((size_t)batch * 8194 + (size_t)(s0 + wm * 128 + c)) * DM + ksb;
    unsigned char* dst = &As[db][wm][0] + wn * 4096;
#pragma unroll
    for (int i = 0; i < 4; ++i) {
      int idx = wn * 256 + i * 64 + lane;
      int row = idx >> 3, ch = idx & 7;
      int cs = ch ^ (row & 7);
      async_ld16(xbp + base + (size_t)row * DM + cs * 8,
                 dst + (i * 64 + lane) * 16);
    }
  };
  // B-half(wn>>1): staged by the 4 waves sharing wn>>1; slice by (wm, wn&1).
  auto stageB = [&](int kt, int db) {
    const int hb = wn >> 1, sl = wm * 2 + (wn & 1);
    unsigned char* dst = &Bs[db][hb][0] + sl * 4096;
#pragma unroll
    for (int i = 0; i < 4; ++i) {
      int idx = sl * 256 + i * 64 + lane;
      int row = idx >> 3, ch = idx & 7;
      int cs = ch ^ (row & 7);
      async_ld16(Wt + (size_t)(n0 + hb * 128 + row) * KD + kt * 64 + cs * 8,
                 dst + (i * 64 + lane) * 16);
    }
  };

  f32x4 acc[8][4];
#pragma unroll
  for (int a = 0; a < 8; ++a)
#pragma unroll
    for (int b = 0; b < 4; ++b) acc[a][b] = (f32x4){0.f, 0.f, 0.f, 0.f};

  short8_t a4[4], b4[4];

  auto rdA = [&](int db, int q, int s) {
    const unsigned char* base = &As[db][wm][0];
#pragma unroll
    for (int mi = 0; mi < 4; ++mi) {
      int r = (q * 4 + mi) * 16 + row16;
      a4[mi] = *(const short8_t*)(base + r * 128 +
                                  (((s << 2) | kgrp) ^ (r & 7)) * 16);
    }
  };
  auto rdB = [&](int db, int s) {
    const unsigned char* base = &Bs[db][wn >> 1][0];
#pragma unroll
    for (int ni = 0; ni < 4; ++ni) {
      int r = (wn & 1) * 64 + ni * 16 + row16;
      b4[ni] = *(const short8_t*)(base + r * 128 +
                                  (((s << 2) | kgrp) ^ (r & 7)) * 16);
    }
  };
  auto mma = [&](int q) {
    __builtin_amdgcn_s_setprio(1);
#pragma unroll
    for (int mi = 0; mi < 4; ++mi)
#pragma unroll
      for (int ni = 0; ni < 4; ++ni)
        acc[q * 4 + mi][ni] = __builtin_amdgcn_mfma_f32_16x16x32_bf16(
            a4[mi], b4[ni], acc[q * 4 + mi][ni], 0, 0, 0);
    __builtin_amdgcn_s_setprio(0);
  };

  // prologue: stage K-step 0 -> db0 and K-step 1 -> db1; confirm K0.
  stageA(0, 0); stageB(0, 0);
  stageA(1, 1); stageB(1, 1);
  asm volatile("s_waitcnt vmcnt(8)" ::: "memory");
  __builtin_amdgcn_s_barrier();

  for (int it = 0; it < 24; ++it) {
    const int k0s = 2 * it;              // db0 K-step (consumed ph0-3)
    const int k1s = 2 * it + 1;          // db1 K-step (consumed ph4-7)
    // 8 phases: (db, q, s, stage)
#pragma unroll
    for (int ph = 0; ph < 8; ++ph) {
      const int db = ph >> 2;            // 0 for ph0-3, 1 for ph4-7
      const int q  = ph & 1;             // m-quadrant
      const int s  = (ph >> 1) & 1;      // k-sub
      // staging: ph0: A(k1s)->db1 (skip it==0: prologue staged K1)
      //          ph2: B(k1s)->db1 ; ph4: A(k0s+2)->db0 ; ph6: B(k0s+2)->db0
      if (ph == 0) { if (it > 0) stageA(k1s, 1); }
      else if (ph == 2) { if (it > 0) stageB(k1s, 1); }
      else if (ph == 4) { if (it < 23) stageA(k0s + 2, 0); }
      else if (ph == 6) { if (it < 23) stageB(k0s + 2, 0); }
      rdA(db, q, s);
      if (q == 0) rdB(db, s);
      __builtin_amdgcn_s_barrier();                       // mid barrier
      asm volatile("s_waitcnt lgkmcnt(0)" ::: "memory");
      __builtin_amdgcn_sched_barrier(0);
      mma(q);
      // drain staged tiles before their consumers' ds_reads (ph3: db1;
      // ph7: db0-next). Loads are 1-3 phases old -> near-free drain.
      if (ph == 3 || ph == 7)
        asm volatile("s_waitcnt vmcnt(0)" ::: "memory");
      __builtin_amdgcn_sched_barrier(0);
      __builtin_amdgcn_s_barrier();                       // end barrier
    }
  }

  // epilogue: C[row=kgrp*4+r, col=row16] per 16x16 fragment
#pragma unroll
  for (int mi = 0; mi < 8; ++mi) {
    size_t grow = m0 + (size_t)(wm * 128 + mi * 16 + kgrp * 4);
#pragma unroll
    for (int ni = 0; ni < 4; ++ni) {
      int col = n0 + wn * 64 + ni * 16 + row16;
      float bia = biasp[col];
      float* op = out + grow * DM + col;
#pragma unroll
      for (int r = 0; r < 4; ++r) op[(size_t)r * DM] = acc[mi][ni][r] + bia;
    }
  }
}

// ---------------- fallback GEMM (fp32 A direct), 128x128 2-barrier ----------
__global__ __launch_bounds__(256) void gemm_fb(const float* __restrict__ Ag,
                                               const unsigned short* __restrict__ Wt,
                                               const float* __restrict__ biasp,
                                               const float* __restrict__ zp,
                                               float* __restrict__ out) {
  __shared__ __align__(16) unsigned char As[128 * 64 * 4];
  __shared__ __align__(16) unsigned char Bs[128 * 64 * 2];

  const int tid = threadIdx.x;
  const int lane = tid & 63;
  const int wid = tid >> 6;
  const int wm = wid >> 1, wn = wid & 1;
  const int row16 = lane & 15, kgrp = lane >> 4;

  const int L = blockIdx.x;
  const int xcd = L & 7;
  const int j = L >> 3;
  const int mtile = xcd * 32 + (j >> 3);
  const int ntile = j & 7;

  const int n0 = ntile * 128;
  const int batch = mtile >> 6;
  const int s0 = (mtile & 63) * 128;
  const size_t m0 = (size_t)mtile * 128;

  f32x4 acc[4][4];
#pragma unroll
  for (int a = 0; a < 4; ++a)
#pragma unroll
    for (int b = 0; b < 4; ++b) acc[a][b] = (f32x4){0.f, 0.f, 0.f, 0.f};

  for (int kt = 0; kt < 48; ++kt) {
    const int c = kt >> 4;
    const int ksb = (kt & 15) * 64;
    __syncthreads();
#pragma unroll
    for (int it = 0; it < 8; ++it) {
      int f16 = it * 256 + tid;
      int row = f16 >> 4, c16 = f16 & 15;
      int c16s = c16 ^ (row & 7);
      int s = s0 + row + c - 1;
      const float* src = (s >= 0 && s < SEQ)
          ? Ag + ((size_t)batch * SEQ + (size_t)s) * DM + ksb + c16s * 4
          : zp + c16s * 4;
      async_ld16(src, As + f16 * 16);
    }
#pragma unroll
    for (int it = 0; it < 4; ++it) {
      int f16 = it * 256 + tid;
      int row = f16 >> 3, c16 = f16 & 7;
      int c16s = c16 ^ (row & 7);
      const unsigned short* src = Wt + (size_t)(n0 + row) * KD + kt * 64 + c16s * 8;
      async_ld16(src, Bs + f16 * 16);
    }
    __syncthreads();

#pragma unroll
    for (int kk = 0; kk < 2; ++kk) {
      short8_t af[4], bfr[4];
#pragma unroll
      for (int mi = 0; mi < 4; ++mi) {
        int r = wm * 64 + mi * 16 + row16;
        int kb = kk * 128 + kgrp * 32;
        f32x4 lo = *(const f32x4*)(As + r * 256 + (kb ^ ((r & 7) << 4)));
        f32x4 hi = *(const f32x4*)(As + r * 256 + ((kb + 16) ^ ((r & 7) << 4)));
        union { short8_t v; unsigned short u[8]; } pk;
        pk.u[0] = f2bf(lo[0]); pk.u[1] = f2bf(lo[1]);
        pk.u[2] = f2bf(lo[2]); pk.u[3] = f2bf(lo[3]);
        pk.u[4] = f2bf(hi[0]); pk.u[5] = f2bf(hi[1]);
        pk.u[6] = f2bf(hi[2]); pk.u[7] = f2bf(hi[3]);
        af[mi] = pk.v;
      }
#pragma unroll
      for (int ni = 0; ni < 4; ++ni) {
        int r = wn * 64 + ni * 16 + row16;
        int kb = kk * 64 + kgrp * 16;
        bfr[ni] = *(const short8_t*)(Bs + r * 128 + (kb ^ ((r & 7) << 4)));
      }
#pragma unroll
      for (int mi = 0; mi < 4; ++mi)
#pragma unroll
        for (int ni = 0; ni < 4; ++ni)
          acc[mi][ni] = __builtin_amdgcn_mfma_f32_16x16x32_bf16(
              af[mi], bfr[ni], acc[mi][ni], 0, 0, 0);
    }
  }

#pragma unroll
  for (int mi = 0; mi < 4; ++mi) {
    size_t grow = m0 + (size_t)(wm * 64 + mi * 16 + kgrp * 4);
#pragma unroll
    for (int ni = 0; ni < 4; ++ni) {
      int col = n0 + wn * 64 + ni * 16 + row16;
      float bia = biasp[col];
      float* op = out + grow * DM + col;
#pragma unroll
      for (int r = 0; r < 4; ++r) op[(size_t)r * DM] = acc[mi][ni][r] + bia;
    }
  }
}

// ---------------- pass 2: grouped (d%7) RMS norm, in-place ----------------
__global__ __launch_bounds__(256) void norm_kernel(float* __restrict__ y,
                                                   const float* __restrict__ gamma) {
  const int tid = threadIdx.x, lane = tid & 63, wv = tid >> 6;
  const size_t row = (size_t)blockIdx.x * 4 + wv;   // one wave per row
  float4* rp = (float4*)(y + row * DM);
  const float4* gp = (const float4*)gamma;
  float4 v[4];
#pragma unroll
  for (int jj = 0; jj < 4; ++jj) v[jj] = rp[jj * 64 + lane];

  float ss[7] = {0.f, 0.f, 0.f, 0.f, 0.f, 0.f, 0.f};
#pragma unroll
  for (int jj = 0; jj < 4; ++jj) {
    const float vv[4] = {v[jj].x, v[jj].y, v[jj].z, v[jj].w};
#pragma unroll
    for (int i = 0; i < 4; ++i) {
      int d = (jj * 64 + lane) * 4 + i;
      int g = d % 7;
      float sq = vv[i] * vv[i];
#pragma unroll
      for (int t = 0; t < 7; ++t) ss[t] += (g == t) ? sq : 0.f;
    }
  }
#pragma unroll
  for (int t = 0; t < 7; ++t) {
#pragma unroll
    for (int off = 32; off >= 1; off >>= 1) ss[t] += __shfl_xor(ss[t], off, 64);
  }
  float inv[7];
#pragma unroll
  for (int t = 0; t < 7; ++t) {
    float cnt = (t < 2) ? 147.f : 146.f;   // D=1024: groups 0,1 have 147 dims
    inv[t] = rsqrtf(ss[t] / cnt + 1e-6f);
  }
#pragma unroll
  for (int jj = 0; jj < 4; ++jj) {
    float4 g4 = gp[jj * 64 + lane];
    const float vv[4] = {v[jj].x, v[jj].y, v[jj].z, v[jj].w};
    const float gg[4] = {g4.x, g4.y, g4.z, g4.w};
    float o[4];
#pragma unroll
    for (int i = 0; i < 4; ++i) {
      int d = (jj * 64 + lane) * 4 + i;
      int g = d % 7;
      float iv = inv[0];
#pragma unroll
      for (int t = 1; t < 7; ++t) iv = (g == t) ? inv[t] : iv;
      o[i] = vv[i] * iv * gg[i];
    }
    rp[jj * 64 + lane] = make_float4(o[0], o[1], o[2], o[3]);
  }
}

extern "C" void kernel_launch(void* const* d_in, const int* in_sizes, int n_in,
                              void* d_out, int out_size, void* d_ws, size_t ws_size,
                              hipStream_t stream) {
  const float* x     = (const float*)d_in[0];
  const float* W     = (const float*)d_in[1];
  const float* b     = (const float*)d_in[2];
  const float* theta = (const float*)d_in[3];
  const float* gamma = (const float*)d_in[4];
  float* out = (float*)d_out;
  (void)in_sizes; (void)n_in; (void)out_size;

  char* ws = (char*)d_ws;
  unsigned short* Wt = (unsigned short*)ws;                 // 6,291,456 B
  float* biasp = (float*)(ws + 6291456);                    // 4 KiB
  float* zp    = (float*)(ws + 6291456 + 4096);             // 4 KiB zeros
  unsigned short* xbp = (unsigned short*)(ws + 6299648);    // 67,158,016 B
  const size_t needA = 6299648 + (size_t)NB * 8194 * DM * 2;

  prep_w<<<dim3(768), dim3(256), 0, stream>>>(W, theta, Wt);
  prep_bias<<<dim3(1), dim3(512), 0, stream>>>(b, theta, biasp, zp);

  if (ws_size >= needA) {
    prep_x<<<dim3(4096), dim3(256), 0, stream>>>(x, xbp);
    gemm256<<<dim3(512), dim3(512), 0, stream>>>(xbp, Wt, biasp, out);
  } else {
    gemm_fb<<<dim3(2048), dim3(256), 0, stream>>>(x, Wt, biasp, zp, out);
  }
  norm_kernel<<<dim3(8192), dim3(256), 0, stream>>>(out, gamma);
}

// Round 14
// 252.731 us; speedup vs baseline: 1.1138x; 1.0270x over previous
//
#include <hip/hip_runtime.h>
#include <hip/hip_bf16.h>
#include <stdint.h>

// eidosNeighborMixer on MI355X:
//   pass 0 (prep_all, fused): W' = rotate(W, theta0+theta1) -> Wt[N][K] bf16;
//            b' = rotate(b) + zero page; xbp = bf16(x) seq-padded.
//   pass 1 : GEMM  out = A @ Wt^T + b'   (A[m,k] = xbp[b][s + k/1024][k%1024])
//            R9 structure (best measured): 256x256 tile, BK=32, 16 waves
//            (4Mx4N, 1024 thr), wave 64x64 (acc 64 VGPR -> 4 waves/SIMD TLP),
//            4-deep LDS ring, global_load_lds staging, XOR chunk swizzle
//            (conflicts 0), counted vmcnt(4), lgkm(0)+setprio MFMA cluster.
//            Measured 53% MfmaUtil = 87% of the 64x64-tile LDS-read roofline
//            (1/32 B/FLOP vs 256 B/cyc LDS): at the structure's ceiling.
//   pass 2 : grouped (d%7) RMS norm, in-place on d_out

#define SEQ 8192
#define NB 4
#define DM 1024
#define KD 3072

typedef __attribute__((ext_vector_type(8))) short short8_t;
typedef __attribute__((ext_vector_type(4))) float f32x4;

__device__ __forceinline__ unsigned short f2bf(float f) {
  union { float f; uint32_t u; } v; v.f = f;
  return (unsigned short)((v.u + 0x7fffu + ((v.u >> 16) & 1u)) >> 16);  // RNE
}

__device__ __forceinline__ void async_ld16(const void* g, void* l) {
  __builtin_amdgcn_global_load_lds(
      (const __attribute__((address_space(1))) uint32_t*)g,
      (__attribute__((address_space(3))) uint32_t*)(uint32_t)(uintptr_t)l,
      16, 0, 0);
}

// -------- prep_all: blocks 0..767 = W rotate+transpose; 768 = bias+zp;
//          769.. = x -> bf16 seq-padded (grid-stride) --------------------
__global__ __launch_bounds__(256) void prep_all(const float* __restrict__ x,
                                                const float* __restrict__ W,
                                                const float* __restrict__ b,
                                                const float* __restrict__ theta,
                                                unsigned short* __restrict__ xbp,
                                                unsigned short* __restrict__ Wt,
                                                float* __restrict__ biasp,
                                                float* __restrict__ zp) {
  const int B0 = blockIdx.x;
  const int t = threadIdx.x;
  if (B0 < 768) {
    __shared__ float csc[32], css[32];
    __shared__ unsigned short tile[64][72];  // [n_local][k_local], padded
    const int bk = B0 % 48, bn = B0 / 48;
    const int k0 = bk * 64, n0 = bn * 64;
    if (t < 32) {
      int d = n0 / 2 + t;
      float ang = theta[d] + theta[512 + d];
      csc[t] = cosf(ang); css[t] = sinf(ang);
    }
    __syncthreads();
#pragma unroll
    for (int i = 0; i < 8; ++i) {
      int idx = i * 256 + t;           // 2048 pairs = 64 k-rows x 32 pairs
      int pr = idx >> 5;               // k row 0..63
      int pc = idx & 31;               // pair col 0..31
      const float2 w2 = *(const float2*)&W[(size_t)(k0 + pr) * DM + n0 + pc * 2];
      float c = csc[pc], s = css[pc];
      tile[pc * 2][pr]     = f2bf(w2.x * c - w2.y * s);
      tile[pc * 2 + 1][pr] = f2bf(w2.x * s + w2.y * c);
    }
    __syncthreads();
#pragma unroll
    for (int i = 0; i < 16; ++i) {
      int idx = i * 256 + t;           // 4096 elems
      int r = idx >> 6, cdx = idx & 63;
      Wt[(size_t)(n0 + r) * KD + k0 + cdx] = tile[r][cdx];
    }
  } else if (B0 == 768) {
#pragma unroll
    for (int p = t; p < 512; p += 256) {
      float ang = theta[p] + theta[512 + p];
      float c = cosf(ang), s = sinf(ang);
      float be = b[2 * p], bo = b[2 * p + 1];
      biasp[2 * p]     = be * c - bo * s;
      biasp[2 * p + 1] = be * s + bo * c;
    }
    ((float4*)zp)[t] = make_float4(0.f, 0.f, 0.f, 0.f);
  } else {
    const size_t total = (size_t)NB * 8194 * 128;  // 16B chunks (8 bf16)
    const size_t nxb = (size_t)(gridDim.x - 769) * 256;
    for (size_t i = (size_t)(B0 - 769) * 256 + t; i < total; i += nxb) {
      int d8 = (int)(i & 127);
      size_t rem = i >> 7;
      int sp = (int)(rem % 8194);
      size_t bb = rem / 8194;
      uint4 o = make_uint4(0u, 0u, 0u, 0u);
      if (sp > 0 && sp < 8193) {
        const float4* src =
            (const float4*)(x + (bb * SEQ + (size_t)(sp - 1)) * DM + d8 * 8);
        float4 lo = src[0], hi = src[1];
        o.x = (uint32_t)f2bf(lo.x) | ((uint32_t)f2bf(lo.y) << 16);
        o.y = (uint32_t)f2bf(lo.z) | ((uint32_t)f2bf(lo.w) << 16);
        o.z = (uint32_t)f2bf(hi.x) | ((uint32_t)f2bf(hi.y) << 16);
        o.w = (uint32_t)f2bf(hi.z) | ((uint32_t)f2bf(hi.w) << 16);
      }
      ((uint4*)xbp)[i] = o;
    }
  }
}

// ---- GEMM: 256x256, BK=32, 16 waves x (64x64), 4-ring, TLP-overlap (R9) ---
__global__ __launch_bounds__(1024, 4) void gemm256(const unsigned short* __restrict__ xbp,
                                                   const unsigned short* __restrict__ Wt,
                                                   const float* __restrict__ biasp,
                                                   float* __restrict__ out) {
  __shared__ __align__(16) unsigned char As[4][16384];  // [buf][256 rows][32 bf16]
  __shared__ __align__(16) unsigned char Bs[4][16384];  // [buf][256 nrow][32 bf16]

  const int tid = threadIdx.x;
  const int lane = tid & 63;
  const int wid = tid >> 6;                   // 0..15
  const int wm = wid >> 2, wn = wid & 3;      // 4M x 4N wave grid
  const int row16 = lane & 15, kgrp = lane >> 4;

  // XCD-bijective swizzle: 512 blocks = 8 XCD x (16 mtiles x 4 ntiles)
  const int L = blockIdx.x;
  const int xcd = L & 7;
  const int j = L >> 3;
  const int mtile = xcd * 16 + (j >> 2);
  const int ntile = j & 3;

  const int n0 = ntile * 256;
  const int batch = mtile >> 5;
  const int s0 = (mtile & 31) * 256;
  const size_t m0 = (size_t)mtile * 256;

  // fragment LDS byte offsets within a 16 KiB buffer (thread-constant)
  int aoff[4], boff[4];
#pragma unroll
  for (int mi = 0; mi < 4; ++mi) {
    int r = wm * 64 + mi * 16 + row16;
    aoff[mi] = r * 64 + (kgrp ^ ((r >> 1) & 3)) * 16;
  }
#pragma unroll
  for (int ni = 0; ni < 4; ++ni) {
    int r = wn * 64 + ni * 16 + row16;
    boff[ni] = r * 64 + (kgrp ^ ((r >> 1) & 3)) * 16;
  }

  // staging: 1024 threads, 1 load each per matrix per K-tile.
  // LDS dest LINEAR; global source chunk pre-swizzled (same XOR as reads).
  const int srow = tid >> 2, sc16 = tid & 3;
  const int scs = sc16 ^ ((srow >> 1) & 3);
  auto stageA = [&](int kt, int buf) {
    const int c = kt >> 5;
    const int ksb = (kt & 31) * 32;
    const size_t base = ((size_t)batch * 8194 + (size_t)(s0 + c)) * DM + ksb;
    async_ld16(xbp + base + (size_t)srow * DM + scs * 8, &As[buf][tid * 16]);
  };
  auto stageB = [&](int kt, int buf) {
    const int kb = kt * 32;
    async_ld16(Wt + (size_t)(n0 + srow) * KD + kb + scs * 8, &Bs[buf][tid * 16]);
  };

  f32x4 acc[4][4];
#pragma unroll
  for (int a = 0; a < 4; ++a)
#pragma unroll
    for (int b = 0; b < 4; ++b) acc[a][b] = (f32x4){0.f, 0.f, 0.f, 0.f};

  // prologue: stage kt 0,1,2 (2 loads each); confirm stage(0); barrier
  stageA(0, 0); stageB(0, 0);
  stageA(1, 1); stageB(1, 1);
  stageA(2, 2); stageB(2, 2);
  asm volatile("s_waitcnt vmcnt(4)" ::: "memory");
  __builtin_amdgcn_s_barrier();

  // per K-tile: stage kt+3, read own 8 frags, lgkm(0) (TLP hides the drain),
  // 16 MFMA under setprio, counted vmcnt, barrier.
  auto body = [&](int kt, int buf, int doStage, int vmN) {
    const int sbuf = (buf + 3) & 3;
    if (doStage) { stageA(kt + 3, sbuf); stageB(kt + 3, sbuf); }
    short8_t af[4], bf[4];
#pragma unroll
    for (int mi = 0; mi < 4; ++mi)
      af[mi] = *(const short8_t*)(&As[buf][0] + aoff[mi]);
#pragma unroll
    for (int ni = 0; ni < 4; ++ni)
      bf[ni] = *(const short8_t*)(&Bs[buf][0] + boff[ni]);
    asm volatile("s_waitcnt lgkmcnt(0)" ::: "memory");
    __builtin_amdgcn_sched_barrier(0);
    __builtin_amdgcn_s_setprio(1);
#pragma unroll
    for (int mi = 0; mi < 4; ++mi)
#pragma unroll
      for (int ni = 0; ni < 4; ++ni)
        acc[mi][ni] = __builtin_amdgcn_mfma_f32_16x16x32_bf16(
            af[mi], bf[ni], acc[mi][ni], 0, 0, 0);
    __builtin_amdgcn_s_setprio(0);
    if (vmN == 4)      asm volatile("s_waitcnt vmcnt(4)" ::: "memory");
    else if (vmN == 2) asm volatile("s_waitcnt vmcnt(2)" ::: "memory");
    else               asm volatile("s_waitcnt vmcnt(0)" ::: "memory");
    __builtin_amdgcn_sched_barrier(0);
    __builtin_amdgcn_s_barrier();
  };

  for (int kt4 = 0; kt4 < 92; kt4 += 4) {
    body(kt4 + 0, 0, 1, 4);
    body(kt4 + 1, 1, 1, 4);
    body(kt4 + 2, 2, 1, 4);
    body(kt4 + 3, 3, 1, 4);
  }
  // tail: kt92 stages kt95; then counted drains per the FIFO ledger
  body(92, 0, 1, 4);
  body(93, 1, 0, 2);
  body(94, 2, 0, 0);
  body(95, 3, 0, 0);

  // epilogue: C[row=kgrp*4+r, col=row16] per 16x16 fragment
#pragma unroll
  for (int mi = 0; mi < 4; ++mi) {
    size_t grow = m0 + (size_t)(wm * 64 + mi * 16 + kgrp * 4);
#pragma unroll
    for (int ni = 0; ni < 4; ++ni) {
      int col = n0 + wn * 64 + ni * 16 + row16;
      float bia = biasp[col];
      float* op = out + grow * DM + col;
#pragma unroll
      for (int r = 0; r < 4; ++r) op[(size_t)r * DM] = acc[mi][ni][r] + bia;
    }
  }
}

// ---------------- fallback GEMM (fp32 A direct), 128x128 2-barrier ----------
__global__ __launch_bounds__(256) void gemm_fb(const float* __restrict__ Ag,
                                               const unsigned short* __restrict__ Wt,
                                               const float* __restrict__ biasp,
                                               const float* __restrict__ zp,
                                               float* __restrict__ out) {
  __shared__ __align__(16) unsigned char As[128 * 64 * 4];
  __shared__ __align__(16) unsigned char Bs[128 * 64 * 2];

  const int tid = threadIdx.x;
  const int lane = tid & 63;
  const int wid = tid >> 6;
  const int wm = wid >> 1, wn = wid & 1;
  const int row16 = lane & 15, kgrp = lane >> 4;

  const int L = blockIdx.x;
  const int xcd = L & 7;
  const int j = L >> 3;
  const int mtile = xcd * 32 + (j >> 3);
  const int ntile = j & 7;

  const int n0 = ntile * 128;
  const int batch = mtile >> 6;
  const int s0 = (mtile & 63) * 128;
  const size_t m0 = (size_t)mtile * 128;

  f32x4 acc[4][4];
#pragma unroll
  for (int a = 0; a < 4; ++a)
#pragma unroll
    for (int b = 0; b < 4; ++b) acc[a][b] = (f32x4){0.f, 0.f, 0.f, 0.f};

  for (int kt = 0; kt < 48; ++kt) {
    const int c = kt >> 4;
    const int ksb = (kt & 15) * 64;
    __syncthreads();
#pragma unroll
    for (int it = 0; it < 8; ++it) {
      int f16 = it * 256 + tid;
      int row = f16 >> 4, c16 = f16 & 15;
      int c16s = c16 ^ (row & 7);
      int s = s0 + row + c - 1;
      const float* src = (s >= 0 && s < SEQ)
          ? Ag + ((size_t)batch * SEQ + (size_t)s) * DM + ksb + c16s * 4
          : zp + c16s * 4;
      async_ld16(src, As + f16 * 16);
    }
#pragma unroll
    for (int it = 0; it < 4; ++it) {
      int f16 = it * 256 + tid;
      int row = f16 >> 3, c16 = f16 & 7;
      int c16s = c16 ^ (row & 7);
      const unsigned short* src = Wt + (size_t)(n0 + row) * KD + kt * 64 + c16s * 8;
      async_ld16(src, Bs + f16 * 16);
    }
    __syncthreads();

#pragma unroll
    for (int kk = 0; kk < 2; ++kk) {
      short8_t af[4], bfr[4];
#pragma unroll
      for (int mi = 0; mi < 4; ++mi) {
        int r = wm * 64 + mi * 16 + row16;
        int kb = kk * 128 + kgrp * 32;
        f32x4 lo = *(const f32x4*)(As + r * 256 + (kb ^ ((r & 7) << 4)));
        f32x4 hi = *(const f32x4*)(As + r * 256 + ((kb + 16) ^ ((r & 7) << 4)));
        union { short8_t v; unsigned short u[8]; } pk;
        pk.u[0] = f2bf(lo[0]); pk.u[1] = f2bf(lo[1]);
        pk.u[2] = f2bf(lo[2]); pk.u[3] = f2bf(lo[3]);
        pk.u[4] = f2bf(hi[0]); pk.u[5] = f2bf(hi[1]);
        pk.u[6] = f2bf(hi[2]); pk.u[7] = f2bf(hi[3]);
        af[mi] = pk.v;
      }
#pragma unroll
      for (int ni = 0; ni < 4; ++ni) {
        int r = wn * 64 + ni * 16 + row16;
        int kb = kk * 64 + kgrp * 16;
        bfr[ni] = *(const short8_t*)(Bs + r * 128 + (kb ^ ((r & 7) << 4)));
      }
#pragma unroll
      for (int mi = 0; mi < 4; ++mi)
#pragma unroll
        for (int ni = 0; ni < 4; ++ni)
          acc[mi][ni] = __builtin_amdgcn_mfma_f32_16x16x32_bf16(
              af[mi], bfr[ni], acc[mi][ni], 0, 0, 0);
    }
  }

#pragma unroll
  for (int mi = 0; mi < 4; ++mi) {
    size_t grow = m0 + (size_t)(wm * 64 + mi * 16 + kgrp * 4);
#pragma unroll
    for (int ni = 0; ni < 4; ++ni) {
      int col = n0 + wn * 64 + ni * 16 + row16;
      float bia = biasp[col];
      float* op = out + grow * DM + col;
#pragma unroll
      for (int r = 0; r < 4; ++r) op[(size_t)r * DM] = acc[mi][ni][r] + bia;
    }
  }
}

// ---------------- pass 2: grouped (d%7) RMS norm, in-place ----------------
__global__ __launch_bounds__(256) void norm_kernel(float* __restrict__ y,
                                                   const float* __restrict__ gamma) {
  const int tid = threadIdx.x, lane = tid & 63, wv = tid >> 6;
  const size_t row = (size_t)blockIdx.x * 4 + wv;   // one wave per row
  float4* rp = (float4*)(y + row * DM);
  const float4* gp = (const float4*)gamma;
  float4 v[4];
#pragma unroll
  for (int jj = 0; jj < 4; ++jj) v[jj] = rp[jj * 64 + lane];

  float ss[7] = {0.f, 0.f, 0.f, 0.f, 0.f, 0.f, 0.f};
#pragma unroll
  for (int jj = 0; jj < 4; ++jj) {
    const float vv[4] = {v[jj].x, v[jj].y, v[jj].z, v[jj].w};
#pragma unroll
    for (int i = 0; i < 4; ++i) {
      int d = (jj * 64 + lane) * 4 + i;
      int g = d % 7;
      float sq = vv[i] * vv[i];
#pragma unroll
      for (int t = 0; t < 7; ++t) ss[t] += (g == t) ? sq : 0.f;
    }
  }
#pragma unroll
  for (int t = 0; t < 7; ++t) {
#pragma unroll
    for (int off = 32; off >= 1; off >>= 1) ss[t] += __shfl_xor(ss[t], off, 64);
  }
  float inv[7];
#pragma unroll
  for (int t = 0; t < 7; ++t) {
    float cnt = (t < 2) ? 147.f : 146.f;   // D=1024: groups 0,1 have 147 dims
    inv[t] = rsqrtf(ss[t] / cnt + 1e-6f);
  }
#pragma unroll
  for (int jj = 0; jj < 4; ++jj) {
    float4 g4 = gp[jj * 64 + lane];
    const float vv[4] = {v[jj].x, v[jj].y, v[jj].z, v[jj].w};
    const float gg[4] = {g4.x, g4.y, g4.z, g4.w};
    float o[4];
#pragma unroll
    for (int i = 0; i < 4; ++i) {
      int d = (jj * 64 + lane) * 4 + i;
      int g = d % 7;
      float iv = inv[0];
#pragma unroll
      for (int t = 1; t < 7; ++t) iv = (g == t) ? inv[t] : iv;
      o[i] = vv[i] * iv * gg[i];
    }
    rp[jj * 64 + lane] = make_float4(o[0], o[1], o[2], o[3]);
  }
}

extern "C" void kernel_launch(void* const* d_in, const int* in_sizes, int n_in,
                              void* d_out, int out_size, void* d_ws, size_t ws_size,
                              hipStream_t stream) {
  const float* x     = (const float*)d_in[0];
  const float* W     = (const float*)d_in[1];
  const float* b     = (const float*)d_in[2];
  const float* theta = (const float*)d_in[3];
  const float* gamma = (const float*)d_in[4];
  float* out = (float*)d_out;
  (void)in_sizes; (void)n_in; (void)out_size;

  char* ws = (char*)d_ws;
  unsigned short* Wt = (unsigned short*)ws;                 // 6,291,456 B
  float* biasp = (float*)(ws + 6291456);                    // 4 KiB
  float* zp    = (float*)(ws + 6291456 + 4096);             // 4 KiB zeros
  unsigned short* xbp = (unsigned short*)(ws + 6299648);    // 67,158,016 B
  const size_t needA = 6299648 + (size_t)NB * 8194 * DM * 2;

  if (ws_size >= needA) {
    prep_all<<<dim3(769 + 4096), dim3(256), 0, stream>>>(
        x, W, b, theta, xbp, Wt, biasp, zp);
    gemm256<<<dim3(512), dim3(1024), 0, stream>>>(xbp, Wt, biasp, out);
  } else {
    prep_all<<<dim3(769), dim3(256), 0, stream>>>(
        x, W, b, theta, (unsigned short*)zp, Wt, biasp, zp);
    gemm_fb<<<dim3(2048), dim3(256), 0, stream>>>(x, Wt, biasp, zp, out);
  }
  norm_kernel<<<dim3(8192), dim3(256), 0, stream>>>(out, gamma);
}